// Round 1
// 420.051 us; speedup vs baseline: 1.0452x; 1.0452x over previous
//
#include <hip/hip_runtime.h>
#include <cfloat>

#define NUM_EMB 50
#define EMB_DIM 192
#define ESTRIDE 196  // padded LDS stride (keeps rows 16B-aligned: 196*4 = 49*16)

// ((r0+r1)+(r2+r3))+((r4+r5)+(r6+r7)) — numpy's 8-accumulator combine tree
__device__ __forceinline__ float np_tree8(const float r[8]) {
#pragma clang fp contract(off)
    return ((r[0] + r[1]) + (r[2] + r[3])) + ((r[4] + r[5]) + (r[6] + r[7]));
}

// Bit-exact replica of np.sum(v*v) over 192 contiguous floats (see prior session):
// pairwise halves of 96, each = 8 stride-8 accumulators + combine tree; products
// rounded separately (contract off).
__device__ float np_sumsq_192(const float* __restrict__ p) {
#pragma clang fp contract(off)
    float tot[2];
#pragma unroll
    for (int h = 0; h < 2; ++h) {
        float r[8];
#pragma unroll
        for (int l = 0; l < 8; ++l) r[l] = 0.f;
        const float* q = p + h * 96;
        for (int t = 0; t < 12; ++t)
#pragma unroll
            for (int l = 0; l < 8; ++l) {
                float v = q[t * 8 + l];
                float pr = v * v;
                r[l] = r[l] + pr;
            }
        tot[h] = np_tree8(r);
    }
    return tot[0] + tot[1];
}

// One thread per row. Fused: distances + argmin + loss + quantized-row write.
//
// KEY CHANGE vs prior version: the embedding operand in the FMA loop is read
// from GLOBAL memory at wave-uniform addresses -> compiler emits s_load into
// SGPRs, and v_fma reads the SGPR directly. This removes the 2400 broadcast
// ds_read_b128 per thread that made the old kernel LDS-pipe-bound (VALUBusy
// was only 40%). LDS (sE) is kept ONLY for the fused coalesced output write.
// Numerics are identical: same values, same sequential-FMA order per k.
__global__ __launch_bounds__(256, 4) void vq_fused(
    const float* __restrict__ x, const float* __restrict__ ew,
    float* __restrict__ out_q, float* __restrict__ out_idx,
    float* __restrict__ out_loss, int N)
{
    __shared__ __align__(16) float sE[NUM_EMB * ESTRIDE];  // write-phase copy source
    __shared__ float sB[NUM_EMB];

    for (int i = threadIdx.x; i < NUM_EMB * EMB_DIM; i += blockDim.x) {
        int k = i / EMB_DIM, j = i - k * EMB_DIM;
        sE[k * ESTRIDE + j] = ew[i];
    }
    __syncthreads();
    if (threadIdx.x < NUM_EMB)
        sB[threadIdx.x] = np_sumsq_192(&sE[threadIdx.x * ESTRIDE]);  // row contiguous
    __syncthreads();

    const int row = blockIdx.x * blockDim.x + threadIdx.x;  // grid = N/256 exact
    const float4* xr = (const float4*)(x + (size_t)row * EMB_DIM);

    float acc[NUM_EMB];
#pragma unroll
    for (int k = 0; k < NUM_EMB; ++k) acc[k] = 0.f;

    float rA[8];
    float aHalf[2];

    for (int m = 0; m < 6; ++m) {  // 6 chunks of 32 floats (one 128B line each)
        float4 f4[8];
#pragma unroll
        for (int q = 0; q < 8; ++q) f4[q] = xr[m * 8 + q];

        // ||f||^2 partials, numpy pairwise structure (halves at m=0..2, 3..5)
        if ((m % 3) == 0) {
#pragma unroll
            for (int l = 0; l < 8; ++l) rA[l] = 0.f;
        }
        {
#pragma clang fp contract(off)
#pragma unroll
            for (int q = 0; q < 8; ++q) {
                float p0 = f4[q].x * f4[q].x; rA[(q * 4 + 0) & 7] = rA[(q * 4 + 0) & 7] + p0;
                float p1 = f4[q].y * f4[q].y; rA[(q * 4 + 1) & 7] = rA[(q * 4 + 1) & 7] + p1;
                float p2 = f4[q].z * f4[q].z; rA[(q * 4 + 2) & 7] = rA[(q * 4 + 2) & 7] + p2;
                float p3 = f4[q].w * f4[q].w; rA[(q * 4 + 3) & 7] = rA[(q * 4 + 3) & 7] + p3;
            }
        }
        if ((m % 3) == 2) aHalf[m / 3] = np_tree8(rA);

        // Sequential-FMA dot chains, ascending j (BLAS order), same as before.
        // e operand now comes from global at WAVE-UNIFORM addresses -> s_load
        // into SGPRs (scalar pipe), zero LDS traffic in this loop.
        const float* eb = ew + m * 32;
#pragma unroll
        for (int k = 0; k < NUM_EMB; ++k) {
            const float* ek = eb + k * EMB_DIM;
            float4 e4[8];
#pragma unroll
            for (int q = 0; q < 8; ++q) e4[q] = *(const float4*)&ek[q * 4];
#pragma unroll
            for (int q = 0; q < 8; ++q) {
                acc[k] = __builtin_fmaf(f4[q].x, e4[q].x, acc[k]);
                acc[k] = __builtin_fmaf(f4[q].y, e4[q].y, acc[k]);
                acc[k] = __builtin_fmaf(f4[q].z, e4[q].z, acc[k]);
                acc[k] = __builtin_fmaf(f4[q].w, e4[q].w, acc[k]);
            }
        }
    }

    float best; int bidx;
    {
#pragma clang fp contract(off)
        float a = aHalf[0] + aHalf[1];
        best = FLT_MAX; bidx = 0;
#pragma unroll
        for (int k = 0; k < NUM_EMB; ++k) {
            float t1 = a + sB[k];     // fl(a + b_k)
            float u  = 2.0f * acc[k]; // exact x2
            float d  = t1 - u;        // fl(t1 - u)
            if (d < best) { best = d; bidx = k; }  // strict <: first-index ties
        }
    }
    out_idx[row] = (float)bidx;

    // loss: per-wave shuffle reduce + one atomic (identical to prior version)
    float contrib = best;
#pragma unroll
    for (int off = 1; off < 64; off <<= 1) contrib += __shfl_xor(contrib, off);
    if ((threadIdx.x & 63) == 0) atomicAdd(out_loss, contrib);

    // Fused coalesced quantized-row write: each wave writes its own 64 rows
    // with the octet pattern (8 consecutive float4 = one full 128B line per
    // row-segment per store instr). bidx exchanged via shfl; values broadcast
    // from the LDS-staged table.
    {
        const int lane = threadIdx.x & 63;
        const int c = lane & 7;
        const int rr = lane >> 3;
        const int waveRow0 = row & ~63;  // first row owned by this wave
#pragma unroll
        for (int g = 0; g < 8; ++g) {
            const int kk = __shfl(bidx, g * 8 + rr);
            const int wrow = waveRow0 + g * 8 + rr;
            float4* qrow = (float4*)(out_q + (size_t)wrow * EMB_DIM);
            const float* erow = &sE[kk * ESTRIDE];
#pragma unroll
            for (int t = 0; t < 6; ++t)
                qrow[c + 8 * t] = *(const float4*)&erow[(c + 8 * t) * 4];
        }
    }
}

__global__ void vq_init(float* out_loss) { out_loss[0] = 0.f; out_loss[1] = 0.f; }

__global__ void vq_finalize(float* __restrict__ out_loss, int N)
{
    double mean = (double)out_loss[0] / ((double)N * (double)EMB_DIM);
    out_loss[0] = (float)(1.25 * mean);  // (1 + BETA) * mean min-dist / elems
    out_loss[1] = 0.f;                   // contrastloss
}

extern "C" void kernel_launch(void* const* d_in, const int* in_sizes, int n_in,
                              void* d_out, int out_size, void* d_ws, size_t ws_size,
                              hipStream_t stream)
{
    const float* x  = (const float*)d_in[0];
    const float* ew = (const float*)d_in[1];
    const int N = in_sizes[0] / EMB_DIM;  // 262144 (divisible by 256)

    float* out_q    = (float*)d_out;
    float* out_idx  = out_q + (size_t)N * EMB_DIM;
    float* out_loss = out_idx + N;

    vq_init<<<1, 1, 0, stream>>>(out_loss);
    vq_fused<<<N / 256, 256, 0, stream>>>(x, ew, out_q, out_idx, out_loss, N);
    vq_finalize<<<1, 1, 0, stream>>>(out_loss, N);
}